// Round 1
// 943.653 us; speedup vs baseline: 1.1671x; 1.1671x over previous
//
#include <hip/hip_runtime.h>
#include <hip/hip_bf16.h>
#include <stdint.h>

// Problem constants
#define BATCH 256
#define SEQT  200
#define IND   128
#define HID   256
#define G3    768   // 3*HID
#define OUTD  118

#define HSTRIDE 264  // h-state LDS row stride in shorts (16B-aligned; 132 dw ≡ 4 mod 32)
#define W0SZ (G3*IND)
#define WHSZ (G3*HID)
#define XSZ  (BATCH*SEQT*IND)   // 6,553,600 floats

#define LOG2E  1.44269504f
#define NLOG2E (-1.44269504f)
#define LOG2E2 2.88539008f

typedef short  short8 __attribute__((ext_vector_type(8)));
typedef float  f32x4  __attribute__((ext_vector_type(4)));
typedef int    i32x4  __attribute__((ext_vector_type(4)));

__device__ __forceinline__ float exp2fast(float x) {
#if __has_builtin(__builtin_amdgcn_exp2f)
    return __builtin_amdgcn_exp2f(x);
#else
    return exp2f(x);
#endif
}

__device__ __forceinline__ unsigned short f2bf(float x) {
    union { float f; uint32_t u; } v; v.f = x;
    uint32_t u = v.u;
    u += 0x7FFF + ((u >> 16) & 1);   // round-to-nearest-even
    return (unsigned short)(u >> 16);
}

// One fused, float4-vectorized conversion kernel: x + all four weight matrices.
// All region sizes are divisible by 4, so a 4-chunk never crosses a boundary.
__global__ void cvt_all(const float* __restrict__ x,
                        const float* __restrict__ w0,  const float* __restrict__ wh0,
                        const float* __restrict__ w1,  const float* __restrict__ wh1,
                        unsigned short* __restrict__ xb,
                        unsigned short* __restrict__ o0,  unsigned short* __restrict__ oh0,
                        unsigned short* __restrict__ o1,  unsigned short* __restrict__ oh1) {
    const int n4 = (XSZ + W0SZ + 3 * WHSZ) / 4;
    int idx = blockIdx.x * blockDim.x + threadIdx.x;
    int stride = gridDim.x * blockDim.x;
    for (int i = idx; i < n4; i += stride) {
        int j = i * 4;
        const float* src; unsigned short* dst;
        if (j < XSZ) { src = x; dst = xb; }
        else {
            j -= XSZ;
            if (j < W0SZ) { src = w0; dst = o0; }
            else {
                j -= W0SZ;
                if (j < WHSZ) { src = wh0; dst = oh0; }
                else {
                    j -= WHSZ;
                    if (j < WHSZ) { src = w1; dst = o1; }
                    else { j -= WHSZ; src = wh1; dst = oh1; }
                }
            }
        }
        float4 v = *(const float4*)(src + j);
        ushort4 o;
        o.x = f2bf(v.x); o.y = f2bf(v.y); o.z = f2bf(v.z); o.w = f2bf(v.w);
        *(ushort4*)(dst + j) = o;
    }
}

// bc = bih + bhh for r,z gates (j < 512); bc = bih for n gate. Both layers.
__global__ void combine_bias(const float* __restrict__ bih0, const float* __restrict__ bhh0,
                             const float* __restrict__ bih1, const float* __restrict__ bhh1,
                             float* __restrict__ bc0, float* __restrict__ bc1) {
    int i = blockIdx.x * blockDim.x + threadIdx.x;
    if (i < G3) bc0[i] = bih0[i] + (i < 2 * HID ? bhh0[i] : 0.0f);
    else if (i < 2 * G3) {
        int j = i - G3;
        bc1[j] = bih1[j] + (j < 2 * HID ? bhh1[j] : 0.0f);
    }
}

// C[M,768] = scale * (A[M,K] @ Bt[768,K]^T + bias), scale = -log2e (r,z) / +2*log2e (n).
// B-in-registers gemm: grid = (M/128, 6). 256 threads = 4 waves; wave owns 32 cols.
// Wave's full B slice (2 jt x K) lives in VGPRs, loaded once. Hot loop per 16-row
// subtile: KS A b128 loads (global direct, L1-served) + 2*KS MFMA + 8 coalesced
// dword stores. Zero LDS, zero barriers. Memory-bound on the 157 MB C write.
template<int K>
__global__ __launch_bounds__(256) void gemm_bn(
    const unsigned short* __restrict__ A,
    const unsigned short* __restrict__ Bt,
    const float* __restrict__ bias,
    float* __restrict__ C)
{
    constexpr int KS = K / 32;
    const int wave = threadIdx.x >> 6;
    const int lane = threadIdx.x & 63;
    const int col  = lane & 15;
    const int quad = lane >> 4;
    const int nb   = blockIdx.y;
    const int g0   = nb * 128 + wave * 32 + col;   // jt0 output column
    const float scl = (nb < 4) ? NLOG2E : LOG2E2;

    // B fragments pinned in registers (16 or 32 VGPRs per jt)
    short8 b[2][KS];
#pragma unroll
    for (int jt = 0; jt < 2; jt++)
#pragma unroll
        for (int ks = 0; ks < KS; ks++)
            b[jt][ks] = *(const short8*)(Bt + (size_t)(g0 + jt * 16) * K + ks * 32 + quad * 8);

    const float bia0 = bias[g0];
    const float bia1 = bias[g0 + 16];

    const int m_panel = blockIdx.x * 128;
#pragma unroll 2
    for (int ms = 0; ms < 8; ms++) {
        const int m0 = m_panel + ms * 16;
        const unsigned short* arow = A + (size_t)(m0 + col) * K;
        short8 a[KS];
#pragma unroll
        for (int ks = 0; ks < KS; ks++)
            a[ks] = *(const short8*)(arow + ks * 32 + quad * 8);

        f32x4 acc0 = (f32x4)(0.0f), acc1 = (f32x4)(0.0f);
#pragma unroll
        for (int ks = 0; ks < KS; ks++) {
            acc0 = __builtin_amdgcn_mfma_f32_16x16x32_bf16(a[ks], b[0][ks], acc0, 0, 0, 0);
            acc1 = __builtin_amdgcn_mfma_f32_16x16x32_bf16(a[ks], b[1][ks], acc1, 0, 0, 0);
        }

        float* crow = C + (size_t)(m0 + quad * 4) * G3 + g0;
#pragma unroll
        for (int r = 0; r < 4; r++) {
            crow[(size_t)r * G3]      = (acc0[r] + bia0) * scl;
            crow[(size_t)r * G3 + 16] = (acc1[r] + bia1) * scl;
        }
    }
}

// GRU scan. 16 WGs x 512 threads (8 waves, 2/SIMD @ 256-reg budget).
// WG owns batches [wg*16,+16); wave owns 32 j-cols (jt0/jt1) x 3 gates.
// In registers (pinned): r,z weights both jt (128 regs) + n-gate jt0 (32 regs).
// In LDS: n-gate jt1 weights (64KB) + double-buffered bf16 h (2x8.3KB).
// Per-step LDS reads: 8 waves x (8 h + 8 wn1) b128 = 128 ops (half of round 4).
__global__ __launch_bounds__(512, 2) void gru_scan(
    const float* __restrict__ gx,            // [B*T,768] pre-scaled exp2 args
    const unsigned short* __restrict__ Whh,  // [768,256] bf16
    const float* __restrict__ bhh,           // [768] (only n-part used)
    unsigned short* __restrict__ h1_out,     // [B*T,256] bf16 or nullptr
    float* __restrict__ hlast)               // [B,256] fp32 or nullptr
{
    __shared__ unsigned short hs[2][16 * HSTRIDE];   // 16,896 B
    __shared__ unsigned short wn1[8 * 8 * 512];      // 65,536 B (n-gate jt1)

    const int b0    = blockIdx.x * 16;
    const int tid   = threadIdx.x;
    const int wave  = tid >> 6;
    const int lane  = tid & 63;
    const int col   = lane & 15;
    const int quad  = lane >> 4;
    const int jbase = wave * 32;
    const int j0    = jbase + col;        // jt0 column
    const int j1    = jbase + 16 + col;   // jt1 column

    // r,z weights (both jt) -> pinned registers: 128 VGPRs
    i32x4 wrz[2][2][8];   // [gate][jt][ks]
#pragma unroll
    for (int g = 0; g < 2; g++)
#pragma unroll
        for (int jt = 0; jt < 2; jt++)
#pragma unroll
            for (int ks = 0; ks < 8; ks++)
                wrz[g][jt][ks] = *(const i32x4*)(
                    Whh + (size_t)(g * HID + jbase + jt * 16 + col) * HID + ks * 32 + quad * 8);

    // n-gate jt0 -> pinned registers: 32 VGPRs
    i32x4 wn0[8];
#pragma unroll
    for (int ks = 0; ks < 8; ks++)
        wn0[ks] = *(const i32x4*)(
            Whh + (size_t)(2 * HID + j0) * HID + ks * 32 + quad * 8);

    // n-gate jt1 -> LDS, per-lane-contiguous fragment order (conflict-free)
    const int wnbase = wave * 4096 + lane * 8;   // shorts
#pragma unroll
    for (int ks = 0; ks < 8; ks++)
        *(short8*)&wn1[wnbase + ks * 512] =
            *(const short8*)(Whh + (size_t)(2 * HID + j1) * HID + ks * 32 + quad * 8);

    for (int i = tid; i < 16 * HSTRIDE; i += 512) hs[0][i] = 0;

    float hreg[2][4] = {};
    float bhn[2] = { bhh[2 * HID + j0], bhh[2 * HID + j1] };

    int gof[4], hof[4];
#pragma unroll
    for (int r = 0; r < 4; r++) {
        int row = (b0 + quad * 4 + r) * SEQT;
        gof[r] = row * G3 + j0;
        hof[r] = row * HID + j0;
    }
    const int abase = col * HSTRIDE + quad * 8;          // A-frag read base (shorts)
    const int wbase = (quad * 4) * HSTRIDE + j0;         // h write base

    __syncthreads();

    for (int t = 0; t < SEQT; t++) {
        const unsigned short* hc = hs[t & 1];
        unsigned short*       hn = hs[(t & 1) ^ 1];

        // pin weight regs: opaque per-iter redefinition blocks remat/sinking
#pragma unroll
        for (int g = 0; g < 2; g++)
#pragma unroll
            for (int jt = 0; jt < 2; jt++)
#pragma unroll
                for (int ks = 0; ks < 8; ks++)
                    asm volatile("" : "+v"(wrz[g][jt][ks]));
#pragma unroll
        for (int ks = 0; ks < 8; ks++)
            asm volatile("" : "+v"(wn0[ks]));

        // gx loads at step top; consumed ~1.5k cycles later in the gate phase
        float gc[3][2][4];   // [gate][jt][r]
#pragma unroll
        for (int r = 0; r < 4; r++)
#pragma unroll
            for (int g3 = 0; g3 < 3; g3++) {
                gc[g3][0][r] = gx[gof[r] + g3 * HID];
                gc[g3][1][r] = gx[gof[r] + g3 * HID + 16];
            }
#pragma unroll
        for (int r = 0; r < 4; r++) gof[r] += G3;

        f32x4 acc[3][2];
#pragma unroll
        for (int g = 0; g < 3; g++)
#pragma unroll
            for (int jt = 0; jt < 2; jt++) acc[g][jt] = (f32x4)(0.0f);

#pragma unroll
        for (int ks = 0; ks < 8; ks++) {
            short8 a = *(const short8*)(&hc[abase + ks * 32]);
            acc[0][0] = __builtin_amdgcn_mfma_f32_16x16x32_bf16(a, __builtin_bit_cast(short8, wrz[0][0][ks]), acc[0][0], 0, 0, 0);
            acc[0][1] = __builtin_amdgcn_mfma_f32_16x16x32_bf16(a, __builtin_bit_cast(short8, wrz[0][1][ks]), acc[0][1], 0, 0, 0);
            acc[1][0] = __builtin_amdgcn_mfma_f32_16x16x32_bf16(a, __builtin_bit_cast(short8, wrz[1][0][ks]), acc[1][0], 0, 0, 0);
            acc[1][1] = __builtin_amdgcn_mfma_f32_16x16x32_bf16(a, __builtin_bit_cast(short8, wrz[1][1][ks]), acc[1][1], 0, 0, 0);
            acc[2][0] = __builtin_amdgcn_mfma_f32_16x16x32_bf16(a, __builtin_bit_cast(short8, wn0[ks]),       acc[2][0], 0, 0, 0);
            short8 b1 = *(const short8*)&wn1[wnbase + ks * 512];
            acc[2][1] = __builtin_amdgcn_mfma_f32_16x16x32_bf16(a, b1, acc[2][1], 0, 0, 0);
        }

        unsigned short hb[2][4];
#pragma unroll
        for (int jt = 0; jt < 2; jt++)
#pragma unroll
            for (int r = 0; r < 4; r++) {
                // sigmoid(p) = 1/(1+exp2(-log2e*p)); gc holds -log2e*(gx+b)
                float er = exp2fast(__builtin_fmaf(acc[0][jt][r], NLOG2E, gc[0][jt][r]));
                float rr = __builtin_amdgcn_rcpf(1.0f + er);
                float ez = exp2fast(__builtin_fmaf(acc[1][jt][r], NLOG2E, gc[1][jt][r]));
                float zz = __builtin_amdgcn_rcpf(1.0f + ez);
                // tanh(p) = 1 - 2/(1+exp2(2*log2e*p)); gc[2] holds 2*log2e*(gx+bih_n)
                float inner = acc[2][jt][r] + bhn[jt];
                float en = exp2fast(__builtin_fmaf(rr * inner, LOG2E2, gc[2][jt][r]));
                float nn = __builtin_fmaf(__builtin_amdgcn_rcpf(1.0f + en), -2.0f, 1.0f);
                float hnew = __builtin_fmaf(zz, hreg[jt][r] - nn, nn);
                hreg[jt][r] = hnew;
                hb[jt][r] = f2bf(hnew);
                hn[wbase + r * HSTRIDE + jt * 16] = hb[jt][r];
            }

        if (h1_out) {
#pragma unroll
            for (int jt = 0; jt < 2; jt++)
#pragma unroll
                for (int r = 0; r < 4; r++)
                    h1_out[hof[r] + jt * 16] = hb[jt][r];
        }
#pragma unroll
        for (int r = 0; r < 4; r++) hof[r] += HID;

        if (hlast && t == SEQT - 1) {
#pragma unroll
            for (int jt = 0; jt < 2; jt++)
#pragma unroll
                for (int r = 0; r < 4; r++)
                    hlast[(b0 + quad * 4 + r) * HID + j0 + jt * 16] = hreg[jt][r];
        }

        __syncthreads();
    }
}

// out[256,118] = hlast[256,256] @ fcW[118,256]^T + fcb
__global__ __launch_bounds__(128) void fc_kernel(
    const float* __restrict__ hlast, const float* __restrict__ W,
    const float* __restrict__ b, float* __restrict__ out)
{
    __shared__ float hsm[HID];
    int bidx = blockIdx.x;
    for (int i = threadIdx.x; i < HID; i += 128) hsm[i] = hlast[(size_t)bidx * HID + i];
    __syncthreads();
    int o = threadIdx.x;
    if (o < OUTD) {
        float acc = b[o];
        const float* wrow = W + (size_t)o * HID;
#pragma unroll 4
        for (int k = 0; k < HID; k++) acc += hsm[k] * wrow[k];
        out[(size_t)bidx * OUTD + o] = acc;
    }
}

extern "C" void kernel_launch(void* const* d_in, const int* in_sizes, int n_in,
                              void* d_out, int out_size, void* d_ws, size_t ws_size,
                              hipStream_t stream) {
    const float* x    = (const float*)d_in[0];
    const float* Wih0 = (const float*)d_in[1];
    const float* Whh0 = (const float*)d_in[2];
    const float* bih0 = (const float*)d_in[3];
    const float* bhh0 = (const float*)d_in[4];
    const float* Wih1 = (const float*)d_in[5];
    const float* Whh1 = (const float*)d_in[6];
    const float* bih1 = (const float*)d_in[7];
    const float* bhh1 = (const float*)d_in[8];
    const float* fcW  = (const float*)d_in[9];
    const float* fcb  = (const float*)d_in[10];
    float* out = (float*)d_out;

    char* ws = (char*)d_ws;
    size_t off = 0;
    auto walloc = [&](size_t bytes) {
        void* p = ws + off;
        off = (off + bytes + 255) & ~(size_t)255;
        return p;
    };

    const int M = BATCH * SEQT;                       // 51200
    float*          gxb  = (float*)         walloc((size_t)M * G3 * 4);   // 157.3 MB
    unsigned short* h1b  = (unsigned short*)walloc((size_t)M * HID * 2);  //  26.2 MB
    unsigned short* w0b  = (unsigned short*)walloc((size_t)W0SZ * 2);
    unsigned short* wh0b = (unsigned short*)walloc((size_t)WHSZ * 2);
    unsigned short* w1b  = (unsigned short*)walloc((size_t)WHSZ * 2);
    unsigned short* wh1b = (unsigned short*)walloc((size_t)WHSZ * 2);
    float*          bc0  = (float*)         walloc(G3 * 4);
    float*          bc1  = (float*)         walloc(G3 * 4);
    float*          hlast= (float*)         walloc((size_t)BATCH * HID * 4);

    // xb (13.1 MB, bf16 x) aliases h1b (26.2 MB): xb is dead before gru_scan
    // first writes h1b (gemm0 completes first on the same stream).
    unsigned short* xb = h1b;

    cvt_all    <<<2048, 256, 0, stream>>>(x, Wih0, Whh0, Wih1, Whh1,
                                          xb, w0b, wh0b, w1b, wh1b);
    combine_bias<<<6,   256, 0, stream>>>(bih0, bhh0, bih1, bhh1, bc0, bc1);

    // layer 0
    gemm_bn<IND><<<dim3(M / 128, 6), 256, 0, stream>>>(xb, w0b, bc0, gxb);
    gru_scan<<<16, 512, 0, stream>>>(gxb, wh0b, bhh0, h1b, nullptr);

    // layer 1
    gemm_bn<HID><<<dim3(M / 128, 6), 256, 0, stream>>>(h1b, w1b, bc1, gxb);
    gru_scan<<<16, 512, 0, stream>>>(gxb, wh1b, bhh1, nullptr, hlast);

    fc_kernel<<<BATCH, 128, 0, stream>>>(hlast, fcW, fcb, out);
}

// Round 2
// 660.178 us; speedup vs baseline: 1.6683x; 1.4294x over previous
//
#include <hip/hip_runtime.h>
#include <hip/hip_bf16.h>
#include <stdint.h>

// Problem constants
#define BATCH 256
#define SEQT  200
#define IND   128
#define HID   256
#define G3    768   // 3*HID
#define OUTD  118

#define HSTRIDE 264  // h-state LDS row stride in shorts (16B-aligned; 132 dw ≡ 4 mod 32)
#define W0SZ (G3*IND)
#define WHSZ (G3*HID)
#define XSZ  (BATCH*SEQT*IND)   // 6,553,600 floats

#define LOG2E  1.44269504f
#define NLOG2E (-1.44269504f)
#define LOG2E2 2.88539008f

typedef short  short8 __attribute__((ext_vector_type(8)));
typedef float  f32x4  __attribute__((ext_vector_type(4)));
typedef int    i32x4  __attribute__((ext_vector_type(4)));

__device__ __forceinline__ float exp2fast(float x) {
#if __has_builtin(__builtin_amdgcn_exp2f)
    return __builtin_amdgcn_exp2f(x);
#else
    return exp2f(x);
#endif
}

__device__ __forceinline__ unsigned short f2bf(float x) {
    union { float f; uint32_t u; } v; v.f = x;
    uint32_t u = v.u;
    u += 0x7FFF + ((u >> 16) & 1);   // round-to-nearest-even
    return (unsigned short)(u >> 16);
}

// One fused, float4-vectorized conversion kernel: x + all four weight matrices.
// All region sizes are divisible by 4, so a 4-chunk never crosses a boundary.
__global__ void cvt_all(const float* __restrict__ x,
                        const float* __restrict__ w0,  const float* __restrict__ wh0,
                        const float* __restrict__ w1,  const float* __restrict__ wh1,
                        unsigned short* __restrict__ xb,
                        unsigned short* __restrict__ o0,  unsigned short* __restrict__ oh0,
                        unsigned short* __restrict__ o1,  unsigned short* __restrict__ oh1) {
    const int n4 = (XSZ + W0SZ + 3 * WHSZ) / 4;
    int idx = blockIdx.x * blockDim.x + threadIdx.x;
    int stride = gridDim.x * blockDim.x;
    for (int i = idx; i < n4; i += stride) {
        int j = i * 4;
        const float* src; unsigned short* dst;
        if (j < XSZ) { src = x; dst = xb; }
        else {
            j -= XSZ;
            if (j < W0SZ) { src = w0; dst = o0; }
            else {
                j -= W0SZ;
                if (j < WHSZ) { src = wh0; dst = oh0; }
                else {
                    j -= WHSZ;
                    if (j < WHSZ) { src = w1; dst = o1; }
                    else { j -= WHSZ; src = wh1; dst = oh1; }
                }
            }
        }
        float4 v = *(const float4*)(src + j);
        ushort4 o;
        o.x = f2bf(v.x); o.y = f2bf(v.y); o.z = f2bf(v.z); o.w = f2bf(v.w);
        *(ushort4*)(dst + j) = o;
    }
}

// bc = bih + bhh for r,z gates (j < 512); bc = bih for n gate. Both layers.
__global__ void combine_bias(const float* __restrict__ bih0, const float* __restrict__ bhh0,
                             const float* __restrict__ bih1, const float* __restrict__ bhh1,
                             float* __restrict__ bc0, float* __restrict__ bc1) {
    int i = blockIdx.x * blockDim.x + threadIdx.x;
    if (i < G3) bc0[i] = bih0[i] + (i < 2 * HID ? bhh0[i] : 0.0f);
    else if (i < 2 * G3) {
        int j = i - G3;
        bc1[j] = bih1[j] + (j < 2 * HID ? bhh1[j] : 0.0f);
    }
}

// C[M,768] = scale * (A[M,K] @ Bt[768,K]^T + bias), scale = -log2e (r,z) / +2*log2e (n).
// B-in-registers gemm: grid = (M/128, 6). 256 threads = 4 waves; wave owns 32 cols.
// Wave's full B slice (2 jt x K) lives in VGPRs, loaded once. Hot loop per 16-row
// subtile: KS A b128 loads (global direct, L1-served) + 2*KS MFMA + 8 coalesced
// dword stores. Zero LDS, zero barriers. Memory-bound on the 157 MB C write.
template<int K>
__global__ __launch_bounds__(256) void gemm_bn(
    const unsigned short* __restrict__ A,
    const unsigned short* __restrict__ Bt,
    const float* __restrict__ bias,
    float* __restrict__ C)
{
    constexpr int KS = K / 32;
    const int wave = threadIdx.x >> 6;
    const int lane = threadIdx.x & 63;
    const int col  = lane & 15;
    const int quad = lane >> 4;
    const int nb   = blockIdx.y;
    const int g0   = nb * 128 + wave * 32 + col;   // jt0 output column
    const float scl = (nb < 4) ? NLOG2E : LOG2E2;

    // B fragments pinned in registers (16 or 32 VGPRs per jt)
    short8 b[2][KS];
#pragma unroll
    for (int jt = 0; jt < 2; jt++)
#pragma unroll
        for (int ks = 0; ks < KS; ks++)
            b[jt][ks] = *(const short8*)(Bt + (size_t)(g0 + jt * 16) * K + ks * 32 + quad * 8);

    const float bia0 = bias[g0];
    const float bia1 = bias[g0 + 16];

    const int m_panel = blockIdx.x * 128;
#pragma unroll 2
    for (int ms = 0; ms < 8; ms++) {
        const int m0 = m_panel + ms * 16;
        const unsigned short* arow = A + (size_t)(m0 + col) * K;
        short8 a[KS];
#pragma unroll
        for (int ks = 0; ks < KS; ks++)
            a[ks] = *(const short8*)(arow + ks * 32 + quad * 8);

        f32x4 acc0 = (f32x4)(0.0f), acc1 = (f32x4)(0.0f);
#pragma unroll
        for (int ks = 0; ks < KS; ks++) {
            acc0 = __builtin_amdgcn_mfma_f32_16x16x32_bf16(a[ks], b[0][ks], acc0, 0, 0, 0);
            acc1 = __builtin_amdgcn_mfma_f32_16x16x32_bf16(a[ks], b[1][ks], acc1, 0, 0, 0);
        }

        float* crow = C + (size_t)(m0 + quad * 4) * G3 + g0;
#pragma unroll
        for (int r = 0; r < 4; r++) {
            crow[(size_t)r * G3]      = (acc0[r] + bia0) * scl;
            crow[(size_t)r * G3 + 16] = (acc1[r] + bia1) * scl;
        }
    }
}

// GRU scan. 64 WGs x 512 threads (8 waves, 2/SIMD @ 256-reg budget).
// WG owns batches [wg*4, +4); wave owns 32 j-cols (jt0/jt1) x 3 gates.
// Batch q sits at MFMA row q*4, so output row quad*4 (r=0) <-> batch quad:
// each lane finishes exactly 2 h-values (jt0/jt1). Unused A rows are zeros
// in LDS (zero-inited once, never written). MFMA count/wave unchanged vs the
// 16-batch layout (padding waste ~470cy/SIMD/step) but gate VALU, ds-write
// and gx loads drop 4x, and 64 CUs carry the scan instead of 16.
// gx for step t+1 is prefetched into registers during step t (no h dep).
__global__ __launch_bounds__(512, 2) void gru_scan(
    const float* __restrict__ gx,            // [B*T,768] pre-scaled exp2 args (+pad)
    const unsigned short* __restrict__ Whh,  // [768,256] bf16
    const float* __restrict__ bhh,           // [768] (only n-part used)
    unsigned short* __restrict__ h1_out,     // [B*T,256] bf16 or nullptr
    float* __restrict__ hlast)               // [B,256] fp32 or nullptr
{
    __shared__ unsigned short hs[2][16 * HSTRIDE];   // 16,896 B
    __shared__ unsigned short wn1[8 * 8 * 512];      // 65,536 B (n-gate jt1)

    const int b0    = blockIdx.x * 4;
    const int tid   = threadIdx.x;
    const int wave  = tid >> 6;
    const int lane  = tid & 63;
    const int col   = lane & 15;
    const int quad  = lane >> 4;
    const int jbase = wave * 32;
    const int j0    = jbase + col;        // jt0 column
    const int j1    = jbase + 16 + col;   // jt1 column

    // r,z weights (both jt) -> pinned registers: 128 VGPRs
    i32x4 wrz[2][2][8];   // [gate][jt][ks]
#pragma unroll
    for (int g = 0; g < 2; g++)
#pragma unroll
        for (int jt = 0; jt < 2; jt++)
#pragma unroll
            for (int ks = 0; ks < 8; ks++)
                wrz[g][jt][ks] = *(const i32x4*)(
                    Whh + (size_t)(g * HID + jbase + jt * 16 + col) * HID + ks * 32 + quad * 8);

    // n-gate jt0 -> pinned registers: 32 VGPRs
    i32x4 wn0[8];
#pragma unroll
    for (int ks = 0; ks < 8; ks++)
        wn0[ks] = *(const i32x4*)(
            Whh + (size_t)(2 * HID + j0) * HID + ks * 32 + quad * 8);

    // n-gate jt1 -> LDS, per-lane-contiguous fragment order (conflict-free)
    const int wnbase = wave * 4096 + lane * 8;   // shorts
#pragma unroll
    for (int ks = 0; ks < 8; ks++)
        *(short8*)&wn1[wnbase + ks * 512] =
            *(const short8*)(Whh + (size_t)(2 * HID + j1) * HID + ks * 32 + quad * 8);

    // zero BOTH h buffers: rows != 0 mod 4 stay zero forever (MFMA padding rows)
    for (int i = tid; i < 2 * 16 * HSTRIDE; i += 512) ((unsigned short*)hs)[i] = 0;

    float hreg[2] = {};
    float bhn[2] = { bhh[2 * HID + j0], bhh[2 * HID + j1] };

    int gof, hof;
    {
        int row = (b0 + quad) * SEQT;
        gof = row * G3 + j0;
        hof = row * HID + j0;
    }
    const int abase = col * HSTRIDE + quad * 8;          // A-frag read base (shorts)
    const int wbase = (quad * 4) * HSTRIDE + j0;         // h write base (row = quad*4)

    __syncthreads();

    // preload gx for t=0
    float gc[3][2];
#pragma unroll
    for (int g3 = 0; g3 < 3; g3++) {
        gc[g3][0] = gx[gof + g3 * HID];
        gc[g3][1] = gx[gof + g3 * HID + 16];
    }
    gof += G3;

    for (int t = 0; t < SEQT; t++) {
        const unsigned short* hc = hs[t & 1];
        unsigned short*       hn = hs[(t & 1) ^ 1];

        // pin weight regs: opaque per-iter redefinition blocks remat/sinking
#pragma unroll
        for (int g = 0; g < 2; g++)
#pragma unroll
            for (int jt = 0; jt < 2; jt++)
#pragma unroll
                for (int ks = 0; ks < 8; ks++)
                    asm volatile("" : "+v"(wrz[g][jt][ks]));
#pragma unroll
        for (int ks = 0; ks < 8; ks++)
            asm volatile("" : "+v"(wn0[ks]));

        // prefetch gx for t+1 (gxb is tail-padded; t=199 loads are discarded)
        float gcn[3][2];
#pragma unroll
        for (int g3 = 0; g3 < 3; g3++) {
            gcn[g3][0] = gx[gof + g3 * HID];
            gcn[g3][1] = gx[gof + g3 * HID + 16];
        }
        gof += G3;

        f32x4 acc[3][2];
#pragma unroll
        for (int g = 0; g < 3; g++)
#pragma unroll
            for (int jt = 0; jt < 2; jt++) acc[g][jt] = (f32x4)(0.0f);

#pragma unroll
        for (int ks = 0; ks < 8; ks++) {
            short8 a = *(const short8*)(&hc[abase + ks * 32]);
            acc[0][0] = __builtin_amdgcn_mfma_f32_16x16x32_bf16(a, __builtin_bit_cast(short8, wrz[0][0][ks]), acc[0][0], 0, 0, 0);
            acc[0][1] = __builtin_amdgcn_mfma_f32_16x16x32_bf16(a, __builtin_bit_cast(short8, wrz[0][1][ks]), acc[0][1], 0, 0, 0);
            acc[1][0] = __builtin_amdgcn_mfma_f32_16x16x32_bf16(a, __builtin_bit_cast(short8, wrz[1][0][ks]), acc[1][0], 0, 0, 0);
            acc[1][1] = __builtin_amdgcn_mfma_f32_16x16x32_bf16(a, __builtin_bit_cast(short8, wrz[1][1][ks]), acc[1][1], 0, 0, 0);
            acc[2][0] = __builtin_amdgcn_mfma_f32_16x16x32_bf16(a, __builtin_bit_cast(short8, wn0[ks]),       acc[2][0], 0, 0, 0);
            short8 b1 = *(const short8*)&wn1[wnbase + ks * 512];
            acc[2][1] = __builtin_amdgcn_mfma_f32_16x16x32_bf16(a, b1, acc[2][1], 0, 0, 0);
        }

        unsigned short hb[2];
#pragma unroll
        for (int jt = 0; jt < 2; jt++) {
            // sigmoid(p) = 1/(1+exp2(-log2e*p)); gc holds -log2e*(gx+b)
            float er = exp2fast(__builtin_fmaf(acc[0][jt][0], NLOG2E, gc[0][jt]));
            float rr = __builtin_amdgcn_rcpf(1.0f + er);
            float ez = exp2fast(__builtin_fmaf(acc[1][jt][0], NLOG2E, gc[1][jt]));
            float zz = __builtin_amdgcn_rcpf(1.0f + ez);
            // tanh(p) = 1 - 2/(1+exp2(2*log2e*p)); gc[2] holds 2*log2e*(gx+bih_n)
            float inner = acc[2][jt][0] + bhn[jt];
            float en = exp2fast(__builtin_fmaf(rr * inner, LOG2E2, gc[2][jt]));
            float nn = __builtin_fmaf(__builtin_amdgcn_rcpf(1.0f + en), -2.0f, 1.0f);
            float hnew = __builtin_fmaf(zz, hreg[jt] - nn, nn);
            hreg[jt] = hnew;
            hb[jt] = f2bf(hnew);
            hn[wbase + jt * 16] = hb[jt];
        }

        if (h1_out) {
            h1_out[hof]      = hb[0];
            h1_out[hof + 16] = hb[1];
        }
        hof += HID;

        if (hlast && t == SEQT - 1) {
            hlast[(b0 + quad) * HID + j0]      = hreg[0];
            hlast[(b0 + quad) * HID + j0 + 16] = hreg[1];
        }

        // rotate prefetched gx into place
#pragma unroll
        for (int g3 = 0; g3 < 3; g3++) {
            gc[g3][0] = gcn[g3][0];
            gc[g3][1] = gcn[g3][1];
        }

        __syncthreads();
    }
}

// out[256,118] = hlast[256,256] @ fcW[118,256]^T + fcb
__global__ __launch_bounds__(128) void fc_kernel(
    const float* __restrict__ hlast, const float* __restrict__ W,
    const float* __restrict__ b, float* __restrict__ out)
{
    __shared__ float hsm[HID];
    int bidx = blockIdx.x;
    for (int i = threadIdx.x; i < HID; i += 128) hsm[i] = hlast[(size_t)bidx * HID + i];
    __syncthreads();
    int o = threadIdx.x;
    if (o < OUTD) {
        float acc = b[o];
        const float* wrow = W + (size_t)o * HID;
#pragma unroll 4
        for (int k = 0; k < HID; k++) acc += hsm[k] * wrow[k];
        out[(size_t)bidx * OUTD + o] = acc;
    }
}

extern "C" void kernel_launch(void* const* d_in, const int* in_sizes, int n_in,
                              void* d_out, int out_size, void* d_ws, size_t ws_size,
                              hipStream_t stream) {
    const float* x    = (const float*)d_in[0];
    const float* Wih0 = (const float*)d_in[1];
    const float* Whh0 = (const float*)d_in[2];
    const float* bih0 = (const float*)d_in[3];
    const float* bhh0 = (const float*)d_in[4];
    const float* Wih1 = (const float*)d_in[5];
    const float* Whh1 = (const float*)d_in[6];
    const float* bih1 = (const float*)d_in[7];
    const float* bhh1 = (const float*)d_in[8];
    const float* fcW  = (const float*)d_in[9];
    const float* fcb  = (const float*)d_in[10];
    float* out = (float*)d_out;

    char* ws = (char*)d_ws;
    size_t off = 0;
    auto walloc = [&](size_t bytes) {
        void* p = ws + off;
        off = (off + bytes + 255) & ~(size_t)255;
        return p;
    };

    const int M = BATCH * SEQT;                       // 51200
    // +4KB tail pad: gru_scan prefetches gx one step past the last row.
    float*          gxb  = (float*)         walloc((size_t)M * G3 * 4 + 4096);
    unsigned short* h1b  = (unsigned short*)walloc((size_t)M * HID * 2);  //  26.2 MB
    unsigned short* w0b  = (unsigned short*)walloc((size_t)W0SZ * 2);
    unsigned short* wh0b = (unsigned short*)walloc((size_t)WHSZ * 2);
    unsigned short* w1b  = (unsigned short*)walloc((size_t)WHSZ * 2);
    unsigned short* wh1b = (unsigned short*)walloc((size_t)WHSZ * 2);
    float*          bc0  = (float*)         walloc(G3 * 4);
    float*          bc1  = (float*)         walloc(G3 * 4);
    float*          hlast= (float*)         walloc((size_t)BATCH * HID * 4);

    // xb (13.1 MB, bf16 x) aliases h1b (26.2 MB): xb is dead before gru_scan
    // first writes h1b (gemm0 completes first on the same stream).
    unsigned short* xb = h1b;

    cvt_all    <<<2048, 256, 0, stream>>>(x, Wih0, Whh0, Wih1, Whh1,
                                          xb, w0b, wh0b, w1b, wh1b);
    combine_bias<<<6,   256, 0, stream>>>(bih0, bhh0, bih1, bhh1, bc0, bc1);

    // layer 0
    gemm_bn<IND><<<dim3(M / 128, 6), 256, 0, stream>>>(xb, w0b, bc0, gxb);
    gru_scan<<<64, 512, 0, stream>>>(gxb, wh0b, bhh0, h1b, nullptr);

    // layer 1
    gemm_bn<HID><<<dim3(M / 128, 6), 256, 0, stream>>>(h1b, w1b, bc1, gxb);
    gru_scan<<<64, 512, 0, stream>>>(gxb, wh1b, bhh1, nullptr, hlast);

    fc_kernel<<<BATCH, 128, 0, stream>>>(hlast, fcW, fcb, out);
}

// Round 4
// 595.198 us; speedup vs baseline: 1.8504x; 1.1092x over previous
//
#include <hip/hip_runtime.h>
#include <hip/hip_bf16.h>
#include <stdint.h>

// Problem constants
#define BATCH 256
#define SEQT  200
#define IND   128
#define HID   256
#define G3    768   // 3*HID
#define OUTD  118

#define HSTRIDE 264  // h-state LDS row stride in shorts (16B-aligned; 132 dw ≡ 4 mod 32)
#define W0SZ (G3*IND)
#define WHSZ (G3*HID)
#define XSZ  (BATCH*SEQT*IND)   // 6,553,600 floats

#define LOG2E  1.44269504f
#define NLOG2E (-1.44269504f)
#define LOG2E2 2.88539008f

typedef short  short8 __attribute__((ext_vector_type(8)));
typedef float  f32x4  __attribute__((ext_vector_type(4)));
typedef int    i32x4  __attribute__((ext_vector_type(4)));

__device__ __forceinline__ float exp2fast(float x) {
#if __has_builtin(__builtin_amdgcn_exp2f)
    return __builtin_amdgcn_exp2f(x);
#else
    return exp2f(x);
#endif
}

__device__ __forceinline__ unsigned short f2bf(float x) {
    union { float f; uint32_t u; } v; v.f = x;
    uint32_t u = v.u;
    u += 0x7FFF + ((u >> 16) & 1);   // round-to-nearest-even
    return (unsigned short)(u >> 16);
}

// One fused, float4-vectorized conversion kernel: x + all four weight matrices.
// All region sizes are divisible by 4, so a 4-chunk never crosses a boundary.
__global__ void cvt_all(const float* __restrict__ x,
                        const float* __restrict__ w0,  const float* __restrict__ wh0,
                        const float* __restrict__ w1,  const float* __restrict__ wh1,
                        unsigned short* __restrict__ xb,
                        unsigned short* __restrict__ o0,  unsigned short* __restrict__ oh0,
                        unsigned short* __restrict__ o1,  unsigned short* __restrict__ oh1) {
    const int n4 = (XSZ + W0SZ + 3 * WHSZ) / 4;
    int idx = blockIdx.x * blockDim.x + threadIdx.x;
    int stride = gridDim.x * blockDim.x;
    for (int i = idx; i < n4; i += stride) {
        int j = i * 4;
        const float* src; unsigned short* dst;
        if (j < XSZ) { src = x; dst = xb; }
        else {
            j -= XSZ;
            if (j < W0SZ) { src = w0; dst = o0; }
            else {
                j -= W0SZ;
                if (j < WHSZ) { src = wh0; dst = oh0; }
                else {
                    j -= WHSZ;
                    if (j < WHSZ) { src = w1; dst = o1; }
                    else { j -= WHSZ; src = wh1; dst = oh1; }
                }
            }
        }
        float4 v = *(const float4*)(src + j);
        ushort4 o;
        o.x = f2bf(v.x); o.y = f2bf(v.y); o.z = f2bf(v.z); o.w = f2bf(v.w);
        *(ushort4*)(dst + j) = o;
    }
}

// bc = bih + bhh for r,z gates (j < 512); bc = bih for n gate. Both layers.
__global__ void combine_bias(const float* __restrict__ bih0, const float* __restrict__ bhh0,
                             const float* __restrict__ bih1, const float* __restrict__ bhh1,
                             float* __restrict__ bc0, float* __restrict__ bc1) {
    int i = blockIdx.x * blockDim.x + threadIdx.x;
    if (i < G3) bc0[i] = bih0[i] + (i < 2 * HID ? bhh0[i] : 0.0f);
    else if (i < 2 * G3) {
        int j = i - G3;
        bc1[j] = bih1[j] + (j < 2 * HID ? bhh1[j] : 0.0f);
    }
}

// C[M,768] = scale * (A[M,K] @ Bt[768,K]^T + bias), scale = -log2e (r,z) / +2*log2e (n).
// grid = (6, M/128): nb = blockIdx.x (fast dim -> the 6 nb-siblings of a panel are
// dispatch-adjacent, keeping the A panel L2/L3-hot across its 6 re-reads).
// A panel [128][K] is staged into LDS with fully-coalesced 16B/lane global loads
// (the old per-fragment A gather was a 64-address 512B-stride gather: TA-issue
// bound, ~16cy/load). LDS rows padded to LSTRIDE = K/8+1 16B-units (odd ->
// col*LSTRIDE spans all 8 bank-groups: conflict-free ds_read_b128 fragments).
// B fragments stay pinned in regs (issued before staging; latency hides under it).
// Roofline: C-write 157 MB -> ~25 us/layer at 6.3 TB/s.
template<int K>
__global__ __launch_bounds__(256) void gemm_bn(
    const unsigned short* __restrict__ A,
    const unsigned short* __restrict__ Bt,
    const float* __restrict__ bias,
    float* __restrict__ C)
{
    constexpr int KS      = K / 32;     // MFMA k-steps
    constexpr int CPR     = K / 8;      // 16B chunks per A row
    constexpr int LSTRIDE = CPR + 1;    // padded LDS row stride (16B units)
    constexpr int NCH     = 128 * CPR;  // chunks per panel
    constexpr int PT      = NCH / 256;  // chunks per thread (16 or 8)

    __shared__ i32x4 sA[128 * LSTRIDE];   // 67.6KB (K=256) / 34.8KB (K=128)

    const int tid  = threadIdx.x;
    const int wave = tid >> 6;
    const int lane = tid & 63;
    const int col  = lane & 15;
    const int quad = lane >> 4;
    const int nb   = blockIdx.x;
    const int g0   = nb * 128 + wave * 32 + col;   // jt0 output column
    const float scl = (nb < 4) ? NLOG2E : LOG2E2;
    const int m_panel = blockIdx.y * 128;

    // B fragments -> regs (issue first: long-latency gathers hide under staging)
    short8 b[2][KS];
#pragma unroll
    for (int jt = 0; jt < 2; jt++)
#pragma unroll
        for (int ks = 0; ks < KS; ks++)
            b[jt][ks] = *(const short8*)(Bt + (size_t)(g0 + jt * 16) * K + ks * 32 + quad * 8);

    // stage A panel -> LDS, coalesced (wave reads 1024B contiguous per instr)
    const unsigned short* ap = A + (size_t)m_panel * K;
    i32x4 st[PT];
#pragma unroll
    for (int i = 0; i < PT; i++)
        st[i] = *(const i32x4*)(ap + (size_t)(i * 256 + tid) * 8);
#pragma unroll
    for (int i = 0; i < PT; i++) {
        int g   = i * 256 + tid;
        int row = g / CPR;          // pow2 -> shift
        int c   = g % CPR;
        sA[row * LSTRIDE + c] = st[i];
    }
    __syncthreads();

    const float bia0 = bias[g0];
    const float bia1 = bias[g0 + 16];

#pragma unroll 2
    for (int ms = 0; ms < 8; ms++) {
        f32x4 acc0 = (f32x4)(0.0f), acc1 = (f32x4)(0.0f);
#pragma unroll
        for (int ks = 0; ks < KS; ks++) {
            short8 a = __builtin_bit_cast(short8,
                sA[(ms * 16 + col) * LSTRIDE + ks * 4 + quad]);
            acc0 = __builtin_amdgcn_mfma_f32_16x16x32_bf16(a, b[0][ks], acc0, 0, 0, 0);
            acc1 = __builtin_amdgcn_mfma_f32_16x16x32_bf16(a, b[1][ks], acc1, 0, 0, 0);
        }

        float* crow = C + (size_t)(m_panel + ms * 16 + quad * 4) * G3 + g0;
#pragma unroll
        for (int r = 0; r < 4; r++) {
            crow[(size_t)r * G3]      = (acc0[r] + bia0) * scl;
            crow[(size_t)r * G3 + 16] = (acc1[r] + bia1) * scl;
        }
    }
}

// GRU scan. 64 WGs x 512 threads (8 waves, 2/SIMD @ 256-reg budget).
// WG owns batches [wg*4, +4); wave owns 32 j-cols (jt0/jt1) x 3 gates.
// Batch q sits at MFMA row q*4, so output row quad*4 (r=0) <-> batch quad:
// each lane finishes exactly 2 h-values (jt0/jt1). Unused A rows are zeros
// in LDS (zero-inited once, never written). gx for step t+1 is prefetched
// into registers during step t (no h dep).
__global__ __launch_bounds__(512, 2) void gru_scan(
    const float* __restrict__ gx,            // [B*T,768] pre-scaled exp2 args (+pad)
    const unsigned short* __restrict__ Whh,  // [768,256] bf16
    const float* __restrict__ bhh,           // [768] (only n-part used)
    unsigned short* __restrict__ h1_out,     // [B*T,256] bf16 or nullptr
    float* __restrict__ hlast)               // [B,256] fp32 or nullptr
{
    __shared__ unsigned short hs[2][16 * HSTRIDE];   // 16,896 B
    __shared__ unsigned short wn1[8 * 8 * 512];      // 65,536 B (n-gate jt1)

    const int b0    = blockIdx.x * 4;
    const int tid   = threadIdx.x;
    const int wave  = tid >> 6;
    const int lane  = tid & 63;
    const int col   = lane & 15;
    const int quad  = lane >> 4;
    const int jbase = wave * 32;
    const int j0    = jbase + col;        // jt0 column
    const int j1    = jbase + 16 + col;   // jt1 column

    // r,z weights (both jt) -> pinned registers: 128 VGPRs
    i32x4 wrz[2][2][8];   // [gate][jt][ks]
#pragma unroll
    for (int g = 0; g < 2; g++)
#pragma unroll
        for (int jt = 0; jt < 2; jt++)
#pragma unroll
            for (int ks = 0; ks < 8; ks++)
                wrz[g][jt][ks] = *(const i32x4*)(
                    Whh + (size_t)(g * HID + jbase + jt * 16 + col) * HID + ks * 32 + quad * 8);

    // n-gate jt0 -> pinned registers: 32 VGPRs
    i32x4 wn0[8];
#pragma unroll
    for (int ks = 0; ks < 8; ks++)
        wn0[ks] = *(const i32x4*)(
            Whh + (size_t)(2 * HID + j0) * HID + ks * 32 + quad * 8);

    // n-gate jt1 -> LDS, per-lane-contiguous fragment order (conflict-free)
    const int wnbase = wave * 4096 + lane * 8;   // shorts
#pragma unroll
    for (int ks = 0; ks < 8; ks++)
        *(short8*)&wn1[wnbase + ks * 512] =
            *(const short8*)(Whh + (size_t)(2 * HID + j1) * HID + ks * 32 + quad * 8);

    // zero BOTH h buffers: rows != 0 mod 4 stay zero forever (MFMA padding rows)
    for (int i = tid; i < 2 * 16 * HSTRIDE; i += 512) ((unsigned short*)hs)[i] = 0;

    float hreg[2] = {};
    float bhn[2] = { bhh[2 * HID + j0], bhh[2 * HID + j1] };

    int gof, hof;
    {
        int row = (b0 + quad) * SEQT;
        gof = row * G3 + j0;
        hof = row * HID + j0;
    }
    const int abase = col * HSTRIDE + quad * 8;          // A-frag read base (shorts)
    const int wbase = (quad * 4) * HSTRIDE + j0;         // h write base (row = quad*4)

    __syncthreads();

    // preload gx for t=0
    float gc[3][2];
#pragma unroll
    for (int g3 = 0; g3 < 3; g3++) {
        gc[g3][0] = gx[gof + g3 * HID];
        gc[g3][1] = gx[gof + g3 * HID + 16];
    }
    gof += G3;

    for (int t = 0; t < SEQT; t++) {
        const unsigned short* hc = hs[t & 1];
        unsigned short*       hn = hs[(t & 1) ^ 1];

        // pin weight regs: opaque per-iter redefinition blocks remat/sinking
#pragma unroll
        for (int g = 0; g < 2; g++)
#pragma unroll
            for (int jt = 0; jt < 2; jt++)
#pragma unroll
                for (int ks = 0; ks < 8; ks++)
                    asm volatile("" : "+v"(wrz[g][jt][ks]));
#pragma unroll
        for (int ks = 0; ks < 8; ks++)
            asm volatile("" : "+v"(wn0[ks]));

        // prefetch gx for t+1 (gxb is tail-padded; t=199 loads are discarded)
        float gcn[3][2];
#pragma unroll
        for (int g3 = 0; g3 < 3; g3++) {
            gcn[g3][0] = gx[gof + g3 * HID];
            gcn[g3][1] = gx[gof + g3 * HID + 16];
        }
        gof += G3;

        f32x4 acc[3][2];
#pragma unroll
        for (int g = 0; g < 3; g++)
#pragma unroll
            for (int jt = 0; jt < 2; jt++) acc[g][jt] = (f32x4)(0.0f);

#pragma unroll
        for (int ks = 0; ks < 8; ks++) {
            short8 a = *(const short8*)(&hc[abase + ks * 32]);
            acc[0][0] = __builtin_amdgcn_mfma_f32_16x16x32_bf16(a, __builtin_bit_cast(short8, wrz[0][0][ks]), acc[0][0], 0, 0, 0);
            acc[0][1] = __builtin_amdgcn_mfma_f32_16x16x32_bf16(a, __builtin_bit_cast(short8, wrz[0][1][ks]), acc[0][1], 0, 0, 0);
            acc[1][0] = __builtin_amdgcn_mfma_f32_16x16x32_bf16(a, __builtin_bit_cast(short8, wrz[1][0][ks]), acc[1][0], 0, 0, 0);
            acc[1][1] = __builtin_amdgcn_mfma_f32_16x16x32_bf16(a, __builtin_bit_cast(short8, wrz[1][1][ks]), acc[1][1], 0, 0, 0);
            acc[2][0] = __builtin_amdgcn_mfma_f32_16x16x32_bf16(a, __builtin_bit_cast(short8, wn0[ks]),       acc[2][0], 0, 0, 0);
            short8 b1 = *(const short8*)&wn1[wnbase + ks * 512];
            acc[2][1] = __builtin_amdgcn_mfma_f32_16x16x32_bf16(a, b1, acc[2][1], 0, 0, 0);
        }

        unsigned short hb[2];
#pragma unroll
        for (int jt = 0; jt < 2; jt++) {
            // sigmoid(p) = 1/(1+exp2(-log2e*p)); gc holds -log2e*(gx+b)
            float er = exp2fast(__builtin_fmaf(acc[0][jt][0], NLOG2E, gc[0][jt]));
            float rr = __builtin_amdgcn_rcpf(1.0f + er);
            float ez = exp2fast(__builtin_fmaf(acc[1][jt][0], NLOG2E, gc[1][jt]));
            float zz = __builtin_amdgcn_rcpf(1.0f + ez);
            // tanh(p) = 1 - 2/(1+exp2(2*log2e*p)); gc[2] holds 2*log2e*(gx+bih_n)
            float inner = acc[2][jt][0] + bhn[jt];
            float en = exp2fast(__builtin_fmaf(rr * inner, LOG2E2, gc[2][jt]));
            float nn = __builtin_fmaf(__builtin_amdgcn_rcpf(1.0f + en), -2.0f, 1.0f);
            float hnew = __builtin_fmaf(zz, hreg[jt] - nn, nn);
            hreg[jt] = hnew;
            hb[jt] = f2bf(hnew);
            hn[wbase + jt * 16] = hb[jt];
        }

        if (h1_out) {
            h1_out[hof]      = hb[0];
            h1_out[hof + 16] = hb[1];
        }
        hof += HID;

        if (hlast && t == SEQT - 1) {
            hlast[(b0 + quad) * HID + j0]      = hreg[0];
            hlast[(b0 + quad) * HID + j0 + 16] = hreg[1];
        }

        // rotate prefetched gx into place
#pragma unroll
        for (int g3 = 0; g3 < 3; g3++) {
            gc[g3][0] = gcn[g3][0];
            gc[g3][1] = gcn[g3][1];
        }

        __syncthreads();
    }
}

// out[256,118] = hlast[256,256] @ fcW[118,256]^T + fcb
__global__ __launch_bounds__(128) void fc_kernel(
    const float* __restrict__ hlast, const float* __restrict__ W,
    const float* __restrict__ b, float* __restrict__ out)
{
    __shared__ float hsm[HID];
    int bidx = blockIdx.x;
    for (int i = threadIdx.x; i < HID; i += 128) hsm[i] = hlast[(size_t)bidx * HID + i];
    __syncthreads();
    int o = threadIdx.x;
    if (o < OUTD) {
        float acc = b[o];
        const float* wrow = W + (size_t)o * HID;
#pragma unroll 4
        for (int k = 0; k < HID; k++) acc += hsm[k] * wrow[k];
        out[(size_t)bidx * OUTD + o] = acc;
    }
}

extern "C" void kernel_launch(void* const* d_in, const int* in_sizes, int n_in,
                              void* d_out, int out_size, void* d_ws, size_t ws_size,
                              hipStream_t stream) {
    const float* x    = (const float*)d_in[0];
    const float* Wih0 = (const float*)d_in[1];
    const float* Whh0 = (const float*)d_in[2];
    const float* bih0 = (const float*)d_in[3];
    const float* bhh0 = (const float*)d_in[4];
    const float* Wih1 = (const float*)d_in[5];
    const float* Whh1 = (const float*)d_in[6];
    const float* bih1 = (const float*)d_in[7];
    const float* bhh1 = (const float*)d_in[8];
    const float* fcW  = (const float*)d_in[9];
    const float* fcb  = (const float*)d_in[10];
    float* out = (float*)d_out;

    char* ws = (char*)d_ws;
    size_t off = 0;
    auto walloc = [&](size_t bytes) {
        void* p = ws + off;
        off = (off + bytes + 255) & ~(size_t)255;
        return p;
    };

    const int M = BATCH * SEQT;                       // 51200
    // +4KB tail pad: gru_scan prefetches gx one step past the last row.
    float*          gxb  = (float*)         walloc((size_t)M * G3 * 4 + 4096);
    unsigned short* h1b  = (unsigned short*)walloc((size_t)M * HID * 2);  //  26.2 MB
    unsigned short* w0b  = (unsigned short*)walloc((size_t)W0SZ * 2);
    unsigned short* wh0b = (unsigned short*)walloc((size_t)WHSZ * 2);
    unsigned short* w1b  = (unsigned short*)walloc((size_t)WHSZ * 2);
    unsigned short* wh1b = (unsigned short*)walloc((size_t)WHSZ * 2);
    float*          bc0  = (float*)         walloc(G3 * 4);
    float*          bc1  = (float*)         walloc(G3 * 4);
    float*          hlast= (float*)         walloc((size_t)BATCH * HID * 4);

    // xb (13.1 MB, bf16 x) aliases h1b (26.2 MB): xb is dead before gru_scan
    // first writes h1b (gemm0 completes first on the same stream).
    unsigned short* xb = h1b;

    cvt_all    <<<2048, 256, 0, stream>>>(x, Wih0, Whh0, Wih1, Whh1,
                                          xb, w0b, wh0b, w1b, wh1b);
    combine_bias<<<6,   256, 0, stream>>>(bih0, bhh0, bih1, bhh1, bc0, bc1);

    // layer 0
    gemm_bn<IND><<<dim3(6, M / 128), 256, 0, stream>>>(xb, w0b, bc0, gxb);
    gru_scan<<<64, 512, 0, stream>>>(gxb, wh0b, bhh0, h1b, nullptr);

    // layer 1
    gemm_bn<HID><<<dim3(6, M / 128), 256, 0, stream>>>(h1b, w1b, bc1, gxb);
    gru_scan<<<64, 512, 0, stream>>>(gxb, wh1b, bhh1, nullptr, hlast);

    fc_kernel<<<BATCH, 128, 0, stream>>>(hlast, fcW, fcb, out);
}